// Round 5
// baseline (156.781 us; speedup 1.0000x reference)
//
#include <hip/hip_runtime.h>

typedef __attribute__((ext_vector_type(8))) short bf16x8;
typedef __attribute__((ext_vector_type(4))) float f32x4;

__device__ __forceinline__ unsigned int f2bf(float f) {
  unsigned int u = __builtin_bit_cast(unsigned int, f);
  return (u + 0x7FFFu + ((u >> 16) & 1u)) >> 16;  // RNE to bf16
}
__device__ __forceinline__ float eluf(float x) {
  return x > 0.f ? x : (__expf(x) - 1.f);
}
__device__ __forceinline__ unsigned int cvt_pk_bf16(float a, float b) {
  unsigned int r;
  asm("v_cvt_pk_bf16_f32 %0, %1, %2" : "=v"(r) : "v"(a), "v"(b));
  return r;  // lo = bf16(a), hi = bf16(b), RNE
}

// ---------------------------------------------------------------------------
// Prep (unchanged, verified): fold repeat-8 into w1 (-> [256][16], K padded
// to 32), fold 4-group mean*0.1 into w5 (-> [16][256]*0.025), bf16 A-fragment
// packing [mt][kt][lane][8].
// ws layout (ushort units): w1p@0 (8192), w2p@8192, w3p@73728, w4p@139264
// (65536 each), w5p@204800 (4096).
// ---------------------------------------------------------------------------
__global__ __launch_bounds__(256) void prep_kernel(
    const float* __restrict__ w1, const float* __restrict__ w2,
    const float* __restrict__ w3, const float* __restrict__ w4,
    const float* __restrict__ w5, unsigned short* __restrict__ ws) {
  int idx = blockIdx.x * 256 + threadIdx.x;  // grid covers exactly 208896
  float v = 0.f;
  if (idx < 8192) {
    int mt = idx >> 9, l = (idx >> 3) & 63, j = idx & 7;
    int o = mt * 16 + (l & 15), c = (l >> 4) * 8 + j;  // c in [0,32)
    if (c < 16) {
      const float* r = w1 + o * 128 + c * 8;
      v = ((r[0] + r[1]) + (r[2] + r[3])) + ((r[4] + r[5]) + (r[6] + r[7]));
    }
  } else if (idx < 204800) {
    int t = idx - 8192;
    int which = t >> 16, e = t & 65535;
    const float* w = (which == 0) ? w2 : (which == 1) ? w3 : w4;
    int mt = e >> 12, kt = (e >> 9) & 7, l = (e >> 3) & 63, j = e & 7;
    int o = mt * 16 + (l & 15), c = kt * 32 + (l >> 4) * 8 + j;
    v = w[o * 256 + c];
  } else {
    int e = idx - 204800;
    int kt = e >> 9, l = (e >> 3) & 63, j = e & 7;
    int d = l & 15, c = kt * 32 + (l >> 4) * 8 + j;
    float s = 0.f;
    if (d < 8) {
      for (int g = 0; g < 4; ++g) s += w5[(g * 8 + d) * 256 + c];
    } else {
      for (int g = 0; g < 4; ++g) s += w5[(32 + g * 8 + (d - 8)) * 256 + c];
    }
    v = 0.025f * s;  // 0.1 * mean over 4 groups
  }
  ws[idx] = (unsigned short)f2bf(v);
}

// ---------------------------------------------------------------------------
// Main: one WG = 64 px of one row, 512 threads / 8 waves.
// Tile split 4(M)x2(N): wave (wm=w>>1, wn=w&1) owns 64 out-ch x 32 px
// = 4x2 frags of mfma_f32_16x16x32_bf16 -> 32 acc regs/wave. Total per-wave
// reg demand ~122 <= 128 => launch_bounds(512,4): 4 waves/SIMD, no spill
// (R3 showed 64-acc waves spill at the 128 cap; R4's 144-reg waves cap at 3).
// N-split (not M) keeps LDS B-read bytes unchanged; A (weights) read 2x but
// L2-resident (400 KB).
// LDS: buf @0: [64 px][stride 528] bf16 in-place activations (33792 B);
//      act0 @33792: [64 px][stride 80] bf16 layer-1 input (K=32, zero-pad).
// MFMA maps (verified): A row=l&15,k=lhi*8+j; B col=l&15,k=lhi*8+j;
// D col=l&15,row=lhi*4+reg.
// ---------------------------------------------------------------------------
#define ACT0 33792

__global__ __launch_bounds__(512, 4) void qca_kernel(
    const float* __restrict__ xcat, const unsigned short* __restrict__ wsu,
    float* __restrict__ out) {
  __shared__ __align__(16) char lds[38912];
  float* xt = reinterpret_cast<float*>(lds);  // [16 c][3 rr][66 xl] fp32 (aliases buf)

  const int tid = threadIdx.x;
  const int w = tid >> 6, l = tid & 63;
  const int l15 = l & 15, lhi = l >> 4;
  const int wm = w >> 1, wn = w & 1;

  const int tile = blockIdx.x << 6;
  const int bimg = tile >> 16;
  const int y = (tile >> 8) & 255;
  const int x0 = tile & 255;  // {0,64,128,192}: never crosses a row

  // --- stencil halo: rows y-1..y+1, cols x0-1..x0+64, 16 channels
  for (int t = tid; t < 16 * 3 * 66; t += 512) {
    int c = t / 198;
    int rem = t - c * 198;
    int rr = rem / 66;
    int xl = rem - rr * 66;
    int gy = y + rr - 1, gx = x0 + xl - 1;
    float v = 0.f;
    if (gy >= 0 && gy < 256 && gx >= 0 && gx < 256)
      v = xcat[(size_t)(bimg * 16 + c) * 65536 + gy * 256 + gx];
    xt[t] = v;
  }
  __syncthreads();

  // --- neighbor sums -> act0 (k=16..31 zeroed for the K=32 MFMA)
  for (int t = tid; t < 2048; t += 512) {
    int p = t & 63, c = t >> 6;  // c in [0,32)
    float v = 0.f;
    if (c < 16) {
      const float* bp = xt + c * 198 + (p + 1);
      v = (bp[-1] + bp[0] + bp[1]) + (bp[65] + bp[67]) +
          (bp[131] + bp[132] + bp[133]);
    }
    reinterpret_cast<unsigned short*>(lds + ACT0)[p * 40 + c] =
        (unsigned short)f2bf(v);
  }
  __syncthreads();

  // per-lane LDS base offsets (fragment variation goes to ds imm)
  const int px = wn * 32 + l15;                 // wave's pixel base + lane
  const int lb_r = px * 528 + lhi * 16;         // B reads (buf @ 0)
  const int lb_w = px * 528 + wm * 128 + lhi * 8;  // epilogue writes
  const int lb_a1 = px * 80 + lhi * 16;         // layer-1 act0 reads

  f32x4 acc[4][2];

  auto epi = [&]() {  // ELU + pack + in-place store of wave's 64ch x 32px tile
#pragma unroll
    for (int mi = 0; mi < 4; ++mi)
#pragma unroll
      for (int ni = 0; ni < 2; ++ni) {
        f32x4 v = acc[mi][ni];
        unsigned int u01 = cvt_pk_bf16(eluf(v[0]), eluf(v[1]));
        unsigned int u23 = cvt_pk_bf16(eluf(v[2]), eluf(v[3]));
        *reinterpret_cast<uint2*>(lds + lb_w + (ni * 8448 + mi * 32)) =
            uint2{u01, u23};
      }
  };

  // --- layer 1: K=32 (16 real + 16 zero); reads act0, writes buf (over xt)
  {
#pragma unroll
    for (int mi = 0; mi < 4; ++mi)
#pragma unroll
      for (int ni = 0; ni < 2; ++ni) acc[mi][ni] = f32x4{0.f, 0.f, 0.f, 0.f};
    const bf16x8* w1v = reinterpret_cast<const bf16x8*>(wsu);
    bf16x8 bq[2];
#pragma unroll
    for (int ni = 0; ni < 2; ++ni)
      bq[ni] = *reinterpret_cast<const bf16x8*>(lds + ACT0 + lb_a1 + ni * 1280);
#pragma unroll
    for (int mi = 0; mi < 4; ++mi) {
      bf16x8 a = w1v[((wm << 2) + mi) * 64 + l];
#pragma unroll
      for (int ni = 0; ni < 2; ++ni)
        acc[mi][ni] = __builtin_amdgcn_mfma_f32_16x16x32_bf16(
            a, bq[ni], acc[mi][ni], 0, 0, 0);
    }
    epi();  // writes buf; all waves only read act0 before this -> no race
    __syncthreads();
  }

  // --- middle layers: K=256, 8 k-steps unrolled, in-place update
  auto mid = [&](const unsigned short* wbase) {
    const bf16x8* wv = reinterpret_cast<const bf16x8*>(wbase);
#pragma unroll
    for (int mi = 0; mi < 4; ++mi)
#pragma unroll
      for (int ni = 0; ni < 2; ++ni) acc[mi][ni] = f32x4{0.f, 0.f, 0.f, 0.f};
#pragma unroll
    for (int kt = 0; kt < 8; ++kt) {
      bf16x8 bq[2];
#pragma unroll
      for (int ni = 0; ni < 2; ++ni)
        bq[ni] = *reinterpret_cast<const bf16x8*>(
            lds + lb_r + (ni * 8448 + kt * 64));
#pragma unroll
      for (int mi = 0; mi < 4; ++mi) {
        bf16x8 a = wv[(((wm << 2) + mi) * 8 + kt) * 64 + l];
#pragma unroll
        for (int ni = 0; ni < 2; ++ni)
          acc[mi][ni] = __builtin_amdgcn_mfma_f32_16x16x32_bf16(
              a, bq[ni], acc[mi][ni], 0, 0, 0);
      }
    }
    __syncthreads();  // all waves done reading buf
    epi();            // in-place write
    __syncthreads();  // all writes visible before next layer's reads
  };

  mid(wsu + 8192);    // layer 2
  mid(wsu + 73728);   // layer 3
  mid(wsu + 139264);  // layer 4

  // --- layer 5: M=16 (folded), waves 0-3 handle 16 px each
  if (w < 4) {
    const bf16x8* w5v = reinterpret_cast<const bf16x8*>(wsu + 204800);
    f32x4 a5 = f32x4{0.f, 0.f, 0.f, 0.f};
    const int p = (w << 4) + l15;
    const int lb5 = p * 528 + lhi * 16;
#pragma unroll
    for (int kt = 0; kt < 8; ++kt) {
      bf16x8 a = w5v[kt * 64 + l];
      bf16x8 b = *reinterpret_cast<const bf16x8*>(lds + lb5 + kt * 64);
      a5 = __builtin_amdgcn_mfma_f32_16x16x32_bf16(a, b, a5, 0, 0, 0);
    }
    int pix = tile + p;
    int rem = pix & 65535;
    float* op = out + (size_t)(pix >> 16) * 1048576 + rem;
#pragma unroll
    for (int r = 0; r < 4; ++r) op[(lhi * 4 + r) * 65536] = a5[r];
  }
}

extern "C" void kernel_launch(void* const* d_in, const int* in_sizes, int n_in,
                              void* d_out, int out_size, void* d_ws,
                              size_t ws_size, hipStream_t stream) {
  const float* xcat = (const float*)d_in[0];
  const float* w1 = (const float*)d_in[1];
  const float* w2 = (const float*)d_in[2];
  const float* w3 = (const float*)d_in[3];
  const float* w4 = (const float*)d_in[4];
  const float* w5 = (const float*)d_in[5];
  unsigned short* ws = (unsigned short*)d_ws;  // 417,792 bytes used
  float* out = (float*)d_out;

  prep_kernel<<<816, 256, 0, stream>>>(w1, w2, w3, w4, w5, ws);
  qca_kernel<<<4096, 512, 0, stream>>>(xcat, ws, out);
}